// Round 1
// baseline (421.686 us; speedup 1.0000x reference)
//
#include <hip/hip_runtime.h>

#define D_DIM 128
#define N_DIM 8192
#define B_DIM 32
#define BK 64

typedef float f32x4 __attribute__((ext_vector_type(4)));
typedef short bf16x8 __attribute__((ext_vector_type(8)));
typedef unsigned short u16;

__device__ __forceinline__ u16 f2bf(float f) {
    unsigned int u = __builtin_bit_cast(unsigned int, f);
    u += 0x7FFFu + ((u >> 16) & 1u);   // round-to-nearest-even
    return (u16)(u >> 16);
}

// Kernel 1: per (kslice, batch) block, compute partial X^T X (128x128) over
// kc rows, plus partial column sums. LDS layout: bf16 [d=128][k=64] with
// XOR swizzle on 16B granules: element (d,k) at d*64 + (((k>>3)^(d&7))*8) + (k&7).
// Reads (ds_read_b128) and writes (ds_write_b64) are both conflict-free.
__global__ __launch_bounds__(256, 2) void cov_partial(
    const float* __restrict__ in, float* __restrict__ ws_p,
    float* __restrict__ ws_s, int kc) {
    __shared__ u16 lds[D_DIM * BK];     // 16 KB
    __shared__ float red[8][D_DIM];     // 4 KB

    const int t    = threadIdx.x;
    const int b    = blockIdx.y;
    const int ks   = blockIdx.x;
    const int dc   = t >> 3;            // 0..31: d-quad (cols of X)
    const int nr   = t & 7;             // 0..7 : n-quad within 32-row half
    const int wv   = t >> 6;            // wave 0..3
    const int lane = t & 63;
    const int m    = lane & 15;
    const int q    = lane >> 4;

    const int nstep = kc / BK;
    const float* src = in + (size_t)b * (N_DIM * D_DIM) + (size_t)ks * kc * D_DIM;

    f32x4 acc[2][8];
#pragma unroll
    for (int r = 0; r < 2; ++r)
#pragma unroll
        for (int c = 0; c < 8; ++c) acc[r][c] = (f32x4)0.0f;

    float sum4[4] = {0.f, 0.f, 0.f, 0.f};

    // buf[sub*4+i] = float4 of row (sub*32 + 4*nr + i), cols 4*dc..4*dc+3
    f32x4 buf[8];
    {
        const float* p = src;
#pragma unroll
        for (int sub = 0; sub < 2; ++sub)
#pragma unroll
            for (int i = 0; i < 4; ++i)
                buf[sub * 4 + i] =
                    *(const f32x4*)(p + (size_t)(sub * 32 + 4 * nr + i) * D_DIM + 4 * dc);
    }

    for (int s = 0; s < nstep; ++s) {
        // column sums (fp32, before conversion)
#pragma unroll
        for (int x = 0; x < 8; ++x)
#pragma unroll
            for (int j = 0; j < 4; ++j) sum4[j] += buf[x][j];

        // in-register 4x4 transpose + fp32->bf16
        ushort4 wvreg[2][4];
#pragma unroll
        for (int sub = 0; sub < 2; ++sub)
#pragma unroll
            for (int j = 0; j < 4; ++j) {
                wvreg[sub][j].x = f2bf(buf[sub * 4 + 0][j]);
                wvreg[sub][j].y = f2bf(buf[sub * 4 + 1][j]);
                wvreg[sub][j].z = f2bf(buf[sub * 4 + 2][j]);
                wvreg[sub][j].w = f2bf(buf[sub * 4 + 3][j]);
            }

        // prefetch next k-step (buf now free)
        if (s + 1 < nstep) {
            const float* p = src + (size_t)(s + 1) * BK * D_DIM;
#pragma unroll
            for (int sub = 0; sub < 2; ++sub)
#pragma unroll
                for (int i = 0; i < 4; ++i)
                    buf[sub * 4 + i] =
                        *(const f32x4*)(p + (size_t)(sub * 32 + 4 * nr + i) * D_DIM + 4 * dc);
        }

        __syncthreads();  // all waves done reading previous tile
#pragma unroll
        for (int sub = 0; sub < 2; ++sub)
#pragma unroll
            for (int j = 0; j < 4; ++j) {
                int d = 4 * dc + j;
                int g = sub * 4 + (nr >> 1);            // 16B granule index (k/8)
                int slot = g ^ (d & 7);                 // swizzle
                int off = d * 64 + slot * 8 + 4 * (nr & 1);
                *(ushort4*)(lds + off) = wvreg[sub][j]; // ds_write_b64
            }
        __syncthreads();

        // MFMA: C = X^T X, so A-fragments and B-fragments are the SAME reads.
        // F[tt]: lane holds rows 16*tt+m, k = h*32 + q*8 + j (j=0..7 contiguous).
#pragma unroll
        for (int h = 0; h < 2; ++h) {
            bf16x8 F[8];
#pragma unroll
            for (int tt = 0; tt < 8; ++tt) {
                int slot = (4 * h + q) ^ (m & 7);
                F[tt] = *(const bf16x8*)(lds + (16 * tt + m) * 64 + slot * 8);
            }
#pragma unroll
            for (int r = 0; r < 2; ++r)
#pragma unroll
                for (int c = 0; c < 8; ++c)
                    acc[r][c] = __builtin_amdgcn_mfma_f32_16x16x32_bf16(
                        F[2 * wv + r], F[c], acc[r][c], 0, 0, 0);
        }
    }

    // reduce column sums across the 8 n-quads
#pragma unroll
    for (int j = 0; j < 4; ++j) red[nr][4 * dc + j] = sum4[j];
    __syncthreads();
    if (t < D_DIM) {
        float ssum = 0.f;
#pragma unroll
        for (int i = 0; i < 8; ++i) ssum += red[i][t];
        ws_s[(size_t)(b * gridDim.x + ks) * D_DIM + t] = ssum;
    }

    // write 128x128 partial product
    // C/D layout (16x16x32): col = lane&15, row = q*4 + i
    float* outp = ws_p + (size_t)(b * gridDim.x + ks) * (D_DIM * D_DIM);
#pragma unroll
    for (int r = 0; r < 2; ++r)
#pragma unroll
        for (int c = 0; c < 8; ++c) {
            int e = 16 * c + m;
            int dbase = 32 * wv + 16 * r + 4 * q;
#pragma unroll
            for (int i = 0; i < 4; ++i)
                outp[(size_t)(dbase + i) * D_DIM + e] = acc[r][c][i];
        }
}

// Kernel 2: sum partials, subtract mean outer product, write cov.
__global__ __launch_bounds__(256) void cov_reduce(
    const float* __restrict__ ws_p, const float* __restrict__ ws_s,
    float* __restrict__ out, int kspl) {
    int b = blockIdx.x >> 6;
    int chunk = blockIdx.x & 63;
    int idx = chunk * 256 + threadIdx.x;   // 0..16383
    __shared__ float ssum[D_DIM];
    if (threadIdx.x < D_DIM) {
        float s = 0.f;
        for (int ks = 0; ks < kspl; ++ks)
            s += ws_s[(size_t)(b * kspl + ks) * D_DIM + threadIdx.x];
        ssum[threadIdx.x] = s;
    }
    __syncthreads();
    float acc = 0.f;
    for (int ks = 0; ks < kspl; ++ks)
        acc += ws_p[(size_t)(b * kspl + ks) * (D_DIM * D_DIM) + idx];
    int d = idx >> 7, e = idx & 127;
    const float invN = 1.0f / (float)N_DIM;
    out[(size_t)b * (D_DIM * D_DIM) + idx] =
        acc * invN - (ssum[d] * invN) * (ssum[e] * invN);
}

extern "C" void kernel_launch(void* const* d_in, const int* in_sizes, int n_in,
                              void* d_out, int out_size, void* d_ws, size_t ws_size,
                              hipStream_t stream) {
    const float* in = (const float*)d_in[0];
    float* out = (float*)d_out;

    // pick largest K-split whose partials fit the workspace
    int kspl = 16;
    while (kspl > 1 &&
           (size_t)kspl * B_DIM * (size_t)(D_DIM * D_DIM + D_DIM) * sizeof(float) > ws_size)
        kspl >>= 1;
    int kc = N_DIM / kspl;

    float* ws_p = (float*)d_ws;
    float* ws_s = ws_p + (size_t)kspl * B_DIM * (D_DIM * D_DIM);

    cov_partial<<<dim3(kspl, B_DIM), 256, 0, stream>>>(in, ws_p, ws_s, kc);
    cov_reduce<<<dim3(B_DIM * 64), 256, 0, stream>>>(ws_p, ws_s, out, kspl);
}

// Round 2
// 207.630 us; speedup vs baseline: 2.0310x; 2.0310x over previous
//
#include <hip/hip_runtime.h>

#define D_DIM 128
#define N_DIM 8192
#define B_DIM 32
#define BK 64

typedef float f32x4 __attribute__((ext_vector_type(4)));
typedef short bf16x8 __attribute__((ext_vector_type(8)));
typedef unsigned short u16;

__device__ __forceinline__ u16 f2bf(float f) {
    unsigned int u = __builtin_bit_cast(unsigned int, f);
    u += 0x7FFFu + ((u >> 16) & 1u);   // round-to-nearest-even
    return (u16)(u >> 16);
}

// Kernel 1: per (kslice, batch) block, compute partial X^T X (128x128) over
// kc rows, plus partial column sums. LDS layout: bf16 [d=128][k=64] with
// XOR swizzle on 16B granules: element (d,k) at d*64 + (((k>>3)^(d&7))*8) + (k&7).
// Partial products are dumped in raw MFMA-fragment order (coalesced float4);
// cov_reduce decodes the layout.
__global__ __launch_bounds__(256, 2) void cov_partial(
    const float* __restrict__ in, float* __restrict__ ws_p,
    float* __restrict__ ws_s, int kc) {
    __shared__ u16 lds[D_DIM * BK];     // 16 KB
    __shared__ float red[8][D_DIM];     // 4 KB

    const int t    = threadIdx.x;
    const int b    = blockIdx.y;
    const int ks   = blockIdx.x;
    const int dc   = t >> 3;            // 0..31: d-quad (cols of X)
    const int nr   = t & 7;             // 0..7 : n-quad within 32-row half
    const int wv   = t >> 6;            // wave 0..3
    const int lane = t & 63;
    const int m    = lane & 15;
    const int q    = lane >> 4;

    const int nstep = kc / BK;
    const float* src = in + (size_t)b * (N_DIM * D_DIM) + (size_t)ks * kc * D_DIM;

    f32x4 acc[2][8];
#pragma unroll
    for (int r = 0; r < 2; ++r)
#pragma unroll
        for (int c = 0; c < 8; ++c) acc[r][c] = (f32x4)0.0f;

    float sum4[4] = {0.f, 0.f, 0.f, 0.f};

    // buf[sub*4+i] = float4 of row (sub*32 + 4*nr + i), cols 4*dc..4*dc+3
    f32x4 buf[8];
    {
        const float* p = src;
#pragma unroll
        for (int sub = 0; sub < 2; ++sub)
#pragma unroll
            for (int i = 0; i < 4; ++i)
                buf[sub * 4 + i] =
                    *(const f32x4*)(p + (size_t)(sub * 32 + 4 * nr + i) * D_DIM + 4 * dc);
    }

    for (int s = 0; s < nstep; ++s) {
        // column sums (fp32, before conversion)
#pragma unroll
        for (int x = 0; x < 8; ++x)
#pragma unroll
            for (int j = 0; j < 4; ++j) sum4[j] += buf[x][j];

        // in-register 4x4 transpose + fp32->bf16
        ushort4 wvreg[2][4];
#pragma unroll
        for (int sub = 0; sub < 2; ++sub)
#pragma unroll
            for (int j = 0; j < 4; ++j) {
                wvreg[sub][j].x = f2bf(buf[sub * 4 + 0][j]);
                wvreg[sub][j].y = f2bf(buf[sub * 4 + 1][j]);
                wvreg[sub][j].z = f2bf(buf[sub * 4 + 2][j]);
                wvreg[sub][j].w = f2bf(buf[sub * 4 + 3][j]);
            }

        // prefetch next k-step (buf now free)
        if (s + 1 < nstep) {
            const float* p = src + (size_t)(s + 1) * BK * D_DIM;
#pragma unroll
            for (int sub = 0; sub < 2; ++sub)
#pragma unroll
                for (int i = 0; i < 4; ++i)
                    buf[sub * 4 + i] =
                        *(const f32x4*)(p + (size_t)(sub * 32 + 4 * nr + i) * D_DIM + 4 * dc);
        }

        __syncthreads();  // all waves done reading previous tile
#pragma unroll
        for (int sub = 0; sub < 2; ++sub)
#pragma unroll
            for (int j = 0; j < 4; ++j) {
                int d = 4 * dc + j;
                int g = sub * 4 + (nr >> 1);            // 16B granule index (k/8)
                int slot = g ^ (d & 7);                 // swizzle
                int off = d * 64 + slot * 8 + 4 * (nr & 1);
                *(ushort4*)(lds + off) = wvreg[sub][j]; // ds_write_b64
            }
        __syncthreads();

        // MFMA: C = X^T X. Column fragments Fcol[0..7] (constant indices) and
        // this wave's two row fragments Frow[0..1] (runtime wv folded into the
        // ADDRESS, never the array index — dynamic local-array indexing
        // demotes to scratch).
#pragma unroll
        for (int h = 0; h < 2; ++h) {
            bf16x8 Fcol[8];
#pragma unroll
            for (int tt = 0; tt < 8; ++tt) {
                int slot = (4 * h + q) ^ (m & 7);
                Fcol[tt] = *(const bf16x8*)(lds + (16 * tt + m) * 64 + slot * 8);
            }
            bf16x8 Frow[2];
#pragma unroll
            for (int r = 0; r < 2; ++r) {
                int row = 32 * wv + 16 * r + m;
                int slot = (4 * h + q) ^ (m & 7);
                Frow[r] = *(const bf16x8*)(lds + row * 64 + slot * 8);
            }
#pragma unroll
            for (int r = 0; r < 2; ++r)
#pragma unroll
                for (int c = 0; c < 8; ++c)
                    acc[r][c] = __builtin_amdgcn_mfma_f32_16x16x32_bf16(
                        Frow[r], Fcol[c], acc[r][c], 0, 0, 0);
        }
    }

    // reduce column sums across the 8 n-quads
#pragma unroll
    for (int j = 0; j < 4; ++j) red[nr][4 * dc + j] = sum4[j];
    __syncthreads();
    if (t < D_DIM) {
        float ssum = 0.f;
#pragma unroll
        for (int i = 0; i < 8; ++i) ssum += red[i][t];
        ws_s[(size_t)(b * gridDim.x + ks) * D_DIM + t] = ssum;
    }

    // Dump partial product in RAW fragment order — fully coalesced float4
    // stores. Flat offset (in floats): t*64 + (r*8+c)*4 + i.
    f32x4* outv = (f32x4*)(ws_p + (size_t)(b * gridDim.x + ks) * (D_DIM * D_DIM));
#pragma unroll
    for (int r = 0; r < 2; ++r)
#pragma unroll
        for (int c = 0; c < 8; ++c)
            outv[t * 16 + r * 8 + c] = acc[r][c];
}

// Kernel 2: sum partials (float4), decode fragment layout, subtract mean
// outer product, write cov. Grid: (B_DIM * 16) blocks x 256 threads; each
// thread owns one float4 of the 16384-float partial chunk.
__global__ __launch_bounds__(256) void cov_reduce(
    const float* __restrict__ ws_p, const float* __restrict__ ws_s,
    float* __restrict__ out, int kspl) {
    int b = blockIdx.x >> 4;
    int chunk = blockIdx.x & 15;
    int g = chunk * 256 + threadIdx.x;   // float4 index, 0..4095

    __shared__ float mean[D_DIM];
    if (threadIdx.x < D_DIM) {
        float s = 0.f;
        for (int ks = 0; ks < kspl; ++ks)
            s += ws_s[(size_t)(b * kspl + ks) * D_DIM + threadIdx.x];
        mean[threadIdx.x] = s * (1.0f / (float)N_DIM);
    }
    __syncthreads();

    const f32x4* pv = (const f32x4*)ws_p;
    f32x4 acc = (f32x4)0.0f;
    for (int ks = 0; ks < kspl; ++ks) {
        f32x4 v = pv[(size_t)(b * kspl + ks) * (D_DIM * D_DIM / 4) + g];
        acc.x += v.x; acc.y += v.y; acc.z += v.z; acc.w += v.w;
    }

    // decode: flat float index f = 4*g + i = t2*64 + (r*8+c)*4 + i
    int t2 = g >> 4;
    int rc = g & 15;
    int r = rc >> 3, c = rc & 7;
    int wv = t2 >> 6;
    int lane = t2 & 63;
    int m = lane & 15;
    int q = lane >> 4;
    int d0 = 32 * wv + 16 * r + 4 * q;
    int e = 16 * c + m;

    const float invN = 1.0f / (float)N_DIM;
    float me = mean[e];
    float* ob = out + (size_t)b * (D_DIM * D_DIM);
#pragma unroll
    for (int i = 0; i < 4; ++i) {
        int d = d0 + i;
        ob[(size_t)d * D_DIM + e] = acc[i] * invN - mean[d] * me;
    }
}

extern "C" void kernel_launch(void* const* d_in, const int* in_sizes, int n_in,
                              void* d_out, int out_size, void* d_ws, size_t ws_size,
                              hipStream_t stream) {
    const float* in = (const float*)d_in[0];
    float* out = (float*)d_out;

    // pick largest K-split whose partials fit the workspace
    int kspl = 16;
    while (kspl > 1 &&
           (size_t)kspl * B_DIM * (size_t)(D_DIM * D_DIM + D_DIM) * sizeof(float) > ws_size)
        kspl >>= 1;
    int kc = N_DIM / kspl;

    float* ws_p = (float*)d_ws;
    float* ws_s = ws_p + (size_t)kspl * B_DIM * (D_DIM * D_DIM);

    cov_partial<<<dim3(kspl, B_DIM), 256, 0, stream>>>(in, ws_p, ws_s, kc);
    cov_reduce<<<dim3(B_DIM * 16), 256, 0, stream>>>(ws_p, ws_s, out, kspl);
}